// Round 10
// baseline (231.960 us; speedup 1.0000x reference)
//
#include <hip/hip_runtime.h>
#include <hip/hip_bf16.h>
#include <math.h>

#define TT 4096
#define EE 8
#define DD 1024
#define HH 1024
#define CAP 4096

typedef __attribute__((ext_vector_type(8))) short bf16x8;
typedef __attribute__((ext_vector_type(4))) float f32x4;
typedef __attribute__((ext_vector_type(8))) unsigned short ushort8;

// async global->LDS, 16B per lane; LDS dest is wave-uniform base + lane*16
#define GLL16(gp, lp)                                                                   \
    __builtin_amdgcn_global_load_lds((__attribute__((address_space(1))) void*)(gp),     \
                                     (__attribute__((address_space(3))) void*)(lp),     \
                                     16, 0, 0)

// ---------------- workspace layout (bytes) ----------------
static const size_t OFF_XB     = 0;                         // bf16 [4096][1024]  8 MB
static const size_t OFF_W1T    = 8u * 1024 * 1024;          // bf16 [8][H][D]    16 MB
static const size_t OFF_W2T    = 24u * 1024 * 1024;         // bf16 [8][D][H]    16 MB
static const size_t OFF_ABUF   = 40u * 1024 * 1024;         // bf16 [8192][1024] 16 MB
static const size_t OFF_OBUF   = 56u * 1024 * 1024;         // f32  [8192][1024] 32 MB
static const size_t OFF_ROWMAP = 88u * 1024 * 1024;         // int  [8][4096]   128 KB
static const size_t OFF_GATES  = OFF_ROWMAP + 8 * CAP * 4;  // f32  [8192]       32 KB
static const size_t OFF_COUNTS = OFF_GATES + 8192 * 4;      // int  [8]
static const size_t OFF_PICKS  = OFF_COUNTS + 256;          // int  [4096]       16 KB

#define NGATE 1024   // gate blocks come FIRST

// ---------------- prep: gating (blocks 0..1023, 1 token/wave) + transpose (1024..5119) --
__global__ __launch_bounds__(256) void prep_kernel(
    const float* __restrict__ x, const float* __restrict__ wg,
    const float* __restrict__ w1, const float* __restrict__ w2,
    __hip_bfloat16* __restrict__ xb,
    __hip_bfloat16* __restrict__ w1t, __hip_bfloat16* __restrict__ w2t,
    int* __restrict__ picks, float* __restrict__ gates)
{
    __shared__ float tl[64][65];
    const int bid = blockIdx.x;
    const int tid = threadIdx.x;

    if (bid >= NGATE) {
        // ---- transpose path: 16 matrices x 256 tiles of 64x64 ----
        const int bt = bid - NGATE;
        const int mat = bt >> 8;
        const int tt = bt & 255;
        const int R = (tt >> 4) * 64;   // src row base (k)
        const int C = (tt & 15) * 64;   // src col base (n)
        const float* src = (mat < EE ? w1 : w2) + (size_t)(mat & 7) * DD * HH;
        __hip_bfloat16* dst = (mat < EE ? w1t : w2t) + (size_t)(mat & 7) * DD * HH;

        const int lrow = tid >> 4;
        const int c4 = tid & 15;
#pragma unroll
        for (int i = 0; i < 4; ++i) {
            const int r = lrow + i * 16;
            float4 v = *(const float4*)(src + (size_t)(R + r) * 1024 + C + c4 * 4);
            tl[r][c4 * 4 + 0] = v.x;
            tl[r][c4 * 4 + 1] = v.y;
            tl[r][c4 * 4 + 2] = v.z;
            tl[r][c4 * 4 + 3] = v.w;
        }
        __syncthreads();
        const int seg = tid & 7;
        const int orow0 = tid >> 3;
#pragma unroll
        for (int p = 0; p < 2; ++p) {
            const int orow = orow0 + p * 32;
            ushort8 u;
#pragma unroll
            for (int j = 0; j < 8; ++j) {
                __hip_bfloat16 h = __float2bfloat16(tl[seg * 8 + j][orow]);
                u[j] = *(unsigned short*)&h;
            }
            *(ushort8*)(dst + (size_t)(C + orow) * 1024 + R + seg * 8) = u;  // one 16B store
        }
        return;
    }

    // ---- gate path: one token per wave ----
    const int lane = tid & 63;
    const int wave = tid >> 6;
    const int t = bid * 4 + wave;
    {
        const float4* xr = (const float4*)(x + (size_t)t * DD);
        ushort4* xbr = (ushort4*)(xb + (size_t)t * DD);

        float acc[EE];
#pragma unroll
        for (int e = 0; e < EE; ++e) acc[e] = 0.f;

#pragma unroll
        for (int c = 0; c < 4; ++c) {
            const int v4 = lane + 64 * c;
            float4 xv = xr[v4];
            __hip_bfloat16 h0 = __float2bfloat16(xv.x);
            __hip_bfloat16 h1 = __float2bfloat16(xv.y);
            __hip_bfloat16 h2 = __float2bfloat16(xv.z);
            __hip_bfloat16 h3 = __float2bfloat16(xv.w);
            ushort4 s;
            s.x = *(unsigned short*)&h0; s.y = *(unsigned short*)&h1;
            s.z = *(unsigned short*)&h2; s.w = *(unsigned short*)&h3;
            xbr[v4] = s;
            const float4* wrow = (const float4*)(wg + (size_t)(4 * v4) * EE);
            const float xs[4] = {xv.x, xv.y, xv.z, xv.w};
#pragma unroll
            for (int q = 0; q < 4; ++q) {
                float4 w0 = wrow[q * 2];
                float4 w1v = wrow[q * 2 + 1];
                acc[0] = fmaf(xs[q], w0.x, acc[0]);
                acc[1] = fmaf(xs[q], w0.y, acc[1]);
                acc[2] = fmaf(xs[q], w0.z, acc[2]);
                acc[3] = fmaf(xs[q], w0.w, acc[3]);
                acc[4] = fmaf(xs[q], w1v.x, acc[4]);
                acc[5] = fmaf(xs[q], w1v.y, acc[5]);
                acc[6] = fmaf(xs[q], w1v.z, acc[6]);
                acc[7] = fmaf(xs[q], w1v.w, acc[7]);
            }
        }
#pragma unroll
        for (int off = 32; off > 0; off >>= 1) {
#pragma unroll
            for (int e = 0; e < EE; ++e) acc[e] += __shfl_xor(acc[e], off, 64);
        }
        if (lane == 0) {
            float mx = acc[0];
#pragma unroll
            for (int e = 1; e < EE; ++e) mx = fmaxf(mx, acc[e]);
            float p[EE];
            float s = 0.f;
#pragma unroll
            for (int e = 0; e < EE; ++e) { p[e] = expf(acc[e] - mx); s += p[e]; }
            int i0 = 0;
#pragma unroll
            for (int e = 1; e < EE; ++e) if (acc[e] > acc[i0]) i0 = e;
            int i1 = (i0 == 0) ? 1 : 0;
#pragma unroll
            for (int e = 0; e < EE; ++e) {
                if (e != i0 && acc[e] > acc[i1]) i1 = e;
            }
            float v0 = p[i0] / s, v1 = p[i1] / s;
            float den = v0 + v1 + 1e-6f;
            gates[t * 2 + 0] = v0 / den;
            gates[t * 2 + 1] = v1 / den;
            picks[t] = i0 | (i1 << 4);
        }
    }
}

// ---------------- bucket build (deterministic, no global atomics) ----------------
__global__ __launch_bounds__(256) void bucket_build(
    const int* __restrict__ picks, int* __restrict__ rowmap, int* __restrict__ counts)
{
    const int e = blockIdx.x;
    const int tid = threadIdx.x;
    const int lane = tid & 63;
    const int wave = tid >> 6;
    __shared__ int wsum[4];

    int runtot = 0;
    for (int tb = 0; tb < TT; tb += 256) {
        const int t = tb + tid;
        const int p = picks[t];
        const int m0 = ((p & 15) == e) ? 1 : 0;
        const int m1 = (((p >> 4) & 15) == e) ? 1 : 0;
        const int c = m0 + m1;
        int incl = c;
#pragma unroll
        for (int off = 1; off < 64; off <<= 1) {
            int v = __shfl_up(incl, off, 64);
            if (lane >= off) incl += v;
        }
        if (lane == 63) wsum[wave] = incl;
        __syncthreads();
        int wbase = 0;
#pragma unroll
        for (int w = 0; w < 4; ++w) wbase += (w < wave) ? wsum[w] : 0;
        int slot = runtot + wbase + incl - c;
        if (m0) { rowmap[e * CAP + slot] = t * 2; slot += 1; }
        if (m1) { rowmap[e * CAP + slot] = t * 2 + 1; }
        runtot += wsum[0] + wsum[1] + wsum[2] + wsum[3];
        __syncthreads();
    }
    if (tid == 0) counts[e] = runtot;
}

// ---------------- grouped GEMM: 128x128, 512 thr, BK=64, XCD-pinned, DOUBLE-BUFFERED ----
// r9 pinning fixed cross-XCD duplication (FETCH 75->~45MB, gemm <40us). Now the drain:
// with the expert's ~4MB working set resident in ONE shared L2, dbuf prefetch cannot
// re-explode FETCH (r5's failure mode); it only overlaps the L2-hit staging latency
// with compute. One barrier per K-iter; prefetch kt+1 issued right after it.
// LDS 64 KB (2 blocks/CU, grid-limited anyway).
// LAYER==1: out = gelu(C + b1) -> bf16 abuf[(t,k) slot]
// LAYER==2: out = (C + b2) * gate -> f32 obuf[(t,k) slot]
template <int LAYER>
__global__ __launch_bounds__(512) void moe_gemm(
    const __hip_bfloat16* __restrict__ Abase,
    const __hip_bfloat16* __restrict__ Bbase,   // [E][N=1024][K=1024], K contiguous
    const float* __restrict__ bias,             // [E][1024]
    const int* __restrict__ rowmap,
    const int* __restrict__ counts,
    const float* __restrict__ gates,
    void* __restrict__ OutP)
{
    // decode: e = XCD selector (fastest) -> expert e's blocks land on XCD e
    const int bid = blockIdx.x;
    const int e = bid & 7;
    const int n0 = ((bid >> 3) & 7) * 128;
    const int m0 = (bid >> 6) * 128;
    const int cnt = counts[e];
    if (m0 >= cnt) return;
    const int tid = threadIdx.x;
    const int lane = tid & 63;
    const int wave = tid >> 6;
    const int wm = (wave >> 2) * 64;   // wave's 64m x 32n quadrant
    const int wn = (wave & 3) * 32;
    const int lrow = lane & 15;
    const int quad = lane >> 4;

    __shared__ __hip_bfloat16 As[2][2][128 * 32];   // [buf][sub] 32 KB
    __shared__ __hip_bfloat16 Bs[2][2][128 * 32];   // 32 KB

    // staging: row = tid>>2 (0..127), 16B chunk = (tid&3)*8 elems; wave w covers rows
    // 16w..16w+15 -> LDS dest = buf + w*1024 + lane*16 (wave-uniform base + lane*16)
    const int ar = m0 + (tid >> 2);
    const int ea = rowmap[e * CAP + (ar < cnt ? ar : 0)];
    const size_t srcA = (size_t)(LAYER == 1 ? (ea >> 1) : ea);
    const __hip_bfloat16* gA = Abase + srcA * DD + (tid & 3) * 8;
    const __hip_bfloat16* Bexp = Bbase + (size_t)e * DD * HH;
    const __hip_bfloat16* gB = Bexp + (size_t)(n0 + (tid >> 2)) * DD + (tid & 3) * 8;

    f32x4 acc[4][2];
#pragma unroll
    for (int i = 0; i < 4; ++i)
#pragma unroll
        for (int j = 0; j < 2; ++j) acc[i][j] = (f32x4){0.f, 0.f, 0.f, 0.f};

#define STAGE(BUF, KT)                                                      \
    {                                                                       \
        _Pragma("unroll") for (int s = 0; s < 2; ++s) {                     \
            const int ko = (KT) * 64 + s * 32;                              \
            GLL16(gA + ko, (char*)&As[BUF][s][0] + wave * 1024);            \
            GLL16(gB + ko, (char*)&Bs[BUF][s][0] + wave * 1024);            \
        }                                                                   \
    }

    STAGE(0, 0);
    for (int kt = 0; kt < DD / 64; ++kt) {
        const int cur = kt & 1;
        __syncthreads();                      // drains cur's staging; frees cur^1 for reuse
        if (kt < DD / 64 - 1) STAGE(cur ^ 1, kt + 1);   // prefetch overlaps compute below

#pragma unroll
        for (int s = 0; s < 2; ++s) {
            const bf16x8* Av = (const bf16x8*)&As[cur][s][0];
            const bf16x8* Bv = (const bf16x8*)&Bs[cur][s][0];
            bf16x8 af[4], bfr[2];
#pragma unroll
            for (int i = 0; i < 4; ++i)
                af[i] = Av[(wm + i * 16 + lrow) * 4 + quad];
#pragma unroll
            for (int i = 0; i < 2; ++i)
                bfr[i] = Bv[(wn + i * 16 + lrow) * 4 + quad];
#pragma unroll
            for (int mi = 0; mi < 4; ++mi)
#pragma unroll
                for (int ni = 0; ni < 2; ++ni)
                    acc[mi][ni] = __builtin_amdgcn_mfma_f32_16x16x32_bf16(
                        af[mi], bfr[ni], acc[mi][ni], 0, 0, 0);
        }
    }
#undef STAGE

    // epilogue: C/D layout col = lane&15, row = quad*4 + reg (m89/m91 verified)
    if (LAYER == 1) {
        __hip_bfloat16* abuf = (__hip_bfloat16*)OutP;
#pragma unroll
        for (int mi = 0; mi < 4; ++mi) {
#pragma unroll
            for (int r = 0; r < 4; ++r) {
                const int mrow = wm + mi * 16 + quad * 4 + r;
                const int gm = m0 + mrow;
                if (gm < cnt) {
                    const int ent = rowmap[e * CAP + gm];
                    __hip_bfloat16* orow = abuf + (size_t)ent * HH + n0 + wn + lrow;
#pragma unroll
                    for (int ni = 0; ni < 2; ++ni) {
                        float v = acc[mi][ni][r] + bias[e * HH + n0 + wn + ni * 16 + lrow];
                        v = 0.5f * v * (1.f + erff(v * 0.70710678118654752f));  // exact GELU
                        orow[ni * 16] = __float2bfloat16(v);
                    }
                }
            }
        }
    } else {
        float* obuf = (float*)OutP;
#pragma unroll
        for (int mi = 0; mi < 4; ++mi) {
#pragma unroll
            for (int r = 0; r < 4; ++r) {
                const int mrow = wm + mi * 16 + quad * 4 + r;
                const int gm = m0 + mrow;
                if (gm < cnt) {
                    const int ent = rowmap[e * CAP + gm];
                    const float g = gates[ent];
                    float* orow = obuf + (size_t)ent * DD + n0 + wn + lrow;
#pragma unroll
                    for (int ni = 0; ni < 2; ++ni) {
                        float v = acc[mi][ni][r] + bias[e * DD + n0 + wn + ni * 16 + lrow];
                        orow[ni * 16] = v * g;
                    }
                }
            }
        }
    }
}

// ---------------- combine: y[t] = o[t,0] + o[t,1] ----------------
__global__ __launch_bounds__(256) void combine_kernel(
    const float* __restrict__ obuf, float* __restrict__ y)
{
    const size_t i = (size_t)blockIdx.x * 256 + threadIdx.x;
    const size_t t = i >> 8;
    const size_t c = i & 255;
    const float4* o0 = (const float4*)(obuf + t * 2 * DD);
    float4 a = o0[c];
    float4 b = o0[256 + c];
    float4 r;
    r.x = a.x + b.x; r.y = a.y + b.y; r.z = a.z + b.z; r.w = a.w + b.w;
    ((float4*)y)[i] = r;
}

extern "C" void kernel_launch(void* const* d_in, const int* in_sizes, int n_in,
                              void* d_out, int out_size, void* d_ws, size_t ws_size,
                              hipStream_t stream)
{
    const float* x  = (const float*)d_in[0];
    const float* w1 = (const float*)d_in[1];
    const float* b1 = (const float*)d_in[2];
    const float* w2 = (const float*)d_in[3];
    const float* b2 = (const float*)d_in[4];
    const float* wg = (const float*)d_in[5];
    float* y = (float*)d_out;

    char* ws = (char*)d_ws;
    __hip_bfloat16* xb   = (__hip_bfloat16*)(ws + OFF_XB);
    __hip_bfloat16* w1t  = (__hip_bfloat16*)(ws + OFF_W1T);
    __hip_bfloat16* w2t  = (__hip_bfloat16*)(ws + OFF_W2T);
    __hip_bfloat16* abuf = (__hip_bfloat16*)(ws + OFF_ABUF);
    float* obuf  = (float*)(ws + OFF_OBUF);
    int*   rowmap = (int*)(ws + OFF_ROWMAP);
    float* gates  = (float*)(ws + OFF_GATES);
    int*   counts = (int*)(ws + OFF_COUNTS);
    int*   picks  = (int*)(ws + OFF_PICKS);

    prep_kernel<<<NGATE + 4096, 256, 0, stream>>>(x, wg, w1, w2, xb, w1t, w2t, picks, gates);
    bucket_build<<<EE, 256, 0, stream>>>(picks, rowmap, counts);
    // 1D grid: id = (m<<6) | (n<<3) | e  -> expert = XCD selector
    moe_gemm<1><<<(CAP / 128) * 8 * EE, 512, 0, stream>>>(
        xb, w1t, b1, rowmap, counts, gates, (void*)abuf);
    moe_gemm<2><<<(CAP / 128) * 8 * EE, 512, 0, stream>>>(
        abuf, w2t, b2, rowmap, counts, gates, (void*)obuf);
    combine_kernel<<<TT * DD / 4 / 256, 256, 0, stream>>>(obuf, y);
}

// Round 11
// 225.402 us; speedup vs baseline: 1.0291x; 1.0291x over previous
//
#include <hip/hip_runtime.h>
#include <hip/hip_bf16.h>
#include <math.h>

#define TT 4096
#define EE 8
#define DD 1024
#define HH 1024
#define CAP 4096

typedef __attribute__((ext_vector_type(8))) short bf16x8;
typedef __attribute__((ext_vector_type(4))) float f32x4;
typedef __attribute__((ext_vector_type(8))) unsigned short ushort8;

// async global->LDS, 16B per lane; LDS dest is wave-uniform base + lane*16
#define GLL16(gp, lp)                                                                   \
    __builtin_amdgcn_global_load_lds((__attribute__((address_space(1))) void*)(gp),     \
                                     (__attribute__((address_space(3))) void*)(lp),     \
                                     16, 0, 0)

// ---------------- workspace layout (bytes) ----------------
static const size_t OFF_XB     = 0;                         // bf16 [4096][1024]  8 MB
static const size_t OFF_W1T    = 8u * 1024 * 1024;          // bf16 [8][H][D]    16 MB
static const size_t OFF_W2T    = 24u * 1024 * 1024;         // bf16 [8][D][H]    16 MB
static const size_t OFF_ABUF   = 40u * 1024 * 1024;         // bf16 [8192][1024] 16 MB
static const size_t OFF_OBUF   = 56u * 1024 * 1024;         // f32  [8192][1024] 32 MB
static const size_t OFF_ROWMAP = 88u * 1024 * 1024;         // int  [8][4096]   128 KB
static const size_t OFF_GATES  = OFF_ROWMAP + 8 * CAP * 4;  // f32  [8192]       32 KB
static const size_t OFF_COUNTS = OFF_GATES + 8192 * 4;      // int  [8]
static const size_t OFF_PICKS  = OFF_COUNTS + 256;          // int  [4096]       16 KB

#define NGATE 1024   // gate blocks come FIRST

// ---------------- prep: gating (blocks 0..1023, 1 token/wave) + transpose (1024..5119) --
__global__ __launch_bounds__(256) void prep_kernel(
    const float* __restrict__ x, const float* __restrict__ wg,
    const float* __restrict__ w1, const float* __restrict__ w2,
    __hip_bfloat16* __restrict__ xb,
    __hip_bfloat16* __restrict__ w1t, __hip_bfloat16* __restrict__ w2t,
    int* __restrict__ picks, float* __restrict__ gates)
{
    __shared__ float tl[64][65];
    const int bid = blockIdx.x;
    const int tid = threadIdx.x;

    if (bid >= NGATE) {
        // ---- transpose path: 16 matrices x 256 tiles of 64x64 ----
        const int bt = bid - NGATE;
        const int mat = bt >> 8;
        const int tt = bt & 255;
        const int R = (tt >> 4) * 64;   // src row base (k)
        const int C = (tt & 15) * 64;   // src col base (n)
        const float* src = (mat < EE ? w1 : w2) + (size_t)(mat & 7) * DD * HH;
        __hip_bfloat16* dst = (mat < EE ? w1t : w2t) + (size_t)(mat & 7) * DD * HH;

        const int lrow = tid >> 4;
        const int c4 = tid & 15;
#pragma unroll
        for (int i = 0; i < 4; ++i) {
            const int r = lrow + i * 16;
            float4 v = *(const float4*)(src + (size_t)(R + r) * 1024 + C + c4 * 4);
            tl[r][c4 * 4 + 0] = v.x;
            tl[r][c4 * 4 + 1] = v.y;
            tl[r][c4 * 4 + 2] = v.z;
            tl[r][c4 * 4 + 3] = v.w;
        }
        __syncthreads();
        const int seg = tid & 7;
        const int orow0 = tid >> 3;
#pragma unroll
        for (int p = 0; p < 2; ++p) {
            const int orow = orow0 + p * 32;
            ushort8 u;
#pragma unroll
            for (int j = 0; j < 8; ++j) {
                __hip_bfloat16 h = __float2bfloat16(tl[seg * 8 + j][orow]);
                u[j] = *(unsigned short*)&h;
            }
            *(ushort8*)(dst + (size_t)(C + orow) * 1024 + R + seg * 8) = u;  // one 16B store
        }
        return;
    }

    // ---- gate path: one token per wave ----
    const int lane = tid & 63;
    const int wave = tid >> 6;
    const int t = bid * 4 + wave;
    {
        const float4* xr = (const float4*)(x + (size_t)t * DD);
        ushort4* xbr = (ushort4*)(xb + (size_t)t * DD);

        float acc[EE];
#pragma unroll
        for (int e = 0; e < EE; ++e) acc[e] = 0.f;

#pragma unroll
        for (int c = 0; c < 4; ++c) {
            const int v4 = lane + 64 * c;
            float4 xv = xr[v4];
            __hip_bfloat16 h0 = __float2bfloat16(xv.x);
            __hip_bfloat16 h1 = __float2bfloat16(xv.y);
            __hip_bfloat16 h2 = __float2bfloat16(xv.z);
            __hip_bfloat16 h3 = __float2bfloat16(xv.w);
            ushort4 s;
            s.x = *(unsigned short*)&h0; s.y = *(unsigned short*)&h1;
            s.z = *(unsigned short*)&h2; s.w = *(unsigned short*)&h3;
            xbr[v4] = s;
            const float4* wrow = (const float4*)(wg + (size_t)(4 * v4) * EE);
            const float xs[4] = {xv.x, xv.y, xv.z, xv.w};
#pragma unroll
            for (int q = 0; q < 4; ++q) {
                float4 w0 = wrow[q * 2];
                float4 w1v = wrow[q * 2 + 1];
                acc[0] = fmaf(xs[q], w0.x, acc[0]);
                acc[1] = fmaf(xs[q], w0.y, acc[1]);
                acc[2] = fmaf(xs[q], w0.z, acc[2]);
                acc[3] = fmaf(xs[q], w0.w, acc[3]);
                acc[4] = fmaf(xs[q], w1v.x, acc[4]);
                acc[5] = fmaf(xs[q], w1v.y, acc[5]);
                acc[6] = fmaf(xs[q], w1v.z, acc[6]);
                acc[7] = fmaf(xs[q], w1v.w, acc[7]);
            }
        }
#pragma unroll
        for (int off = 32; off > 0; off >>= 1) {
#pragma unroll
            for (int e = 0; e < EE; ++e) acc[e] += __shfl_xor(acc[e], off, 64);
        }
        if (lane == 0) {
            float mx = acc[0];
#pragma unroll
            for (int e = 1; e < EE; ++e) mx = fmaxf(mx, acc[e]);
            float p[EE];
            float s = 0.f;
#pragma unroll
            for (int e = 0; e < EE; ++e) { p[e] = expf(acc[e] - mx); s += p[e]; }
            int i0 = 0;
#pragma unroll
            for (int e = 1; e < EE; ++e) if (acc[e] > acc[i0]) i0 = e;
            int i1 = (i0 == 0) ? 1 : 0;
#pragma unroll
            for (int e = 0; e < EE; ++e) {
                if (e != i0 && acc[e] > acc[i1]) i1 = e;
            }
            float v0 = p[i0] / s, v1 = p[i1] / s;
            float den = v0 + v1 + 1e-6f;
            gates[t * 2 + 0] = v0 / den;
            gates[t * 2 + 1] = v1 / den;
            picks[t] = i0 | (i1 << 4);
        }
    }
}

// ---------------- bucket build (deterministic, no global atomics) ----------------
__global__ __launch_bounds__(256) void bucket_build(
    const int* __restrict__ picks, int* __restrict__ rowmap, int* __restrict__ counts)
{
    const int e = blockIdx.x;
    const int tid = threadIdx.x;
    const int lane = tid & 63;
    const int wave = tid >> 6;
    __shared__ int wsum[4];

    int runtot = 0;
    for (int tb = 0; tb < TT; tb += 256) {
        const int t = tb + tid;
        const int p = picks[t];
        const int m0 = ((p & 15) == e) ? 1 : 0;
        const int m1 = (((p >> 4) & 15) == e) ? 1 : 0;
        const int c = m0 + m1;
        int incl = c;
#pragma unroll
        for (int off = 1; off < 64; off <<= 1) {
            int v = __shfl_up(incl, off, 64);
            if (lane >= off) incl += v;
        }
        if (lane == 63) wsum[wave] = incl;
        __syncthreads();
        int wbase = 0;
#pragma unroll
        for (int w = 0; w < 4; ++w) wbase += (w < wave) ? wsum[w] : 0;
        int slot = runtot + wbase + incl - c;
        if (m0) { rowmap[e * CAP + slot] = t * 2; slot += 1; }
        if (m1) { rowmap[e * CAP + slot] = t * 2 + 1; }
        runtot += wsum[0] + wsum[1] + wsum[2] + wsum[3];
        __syncthreads();
    }
    if (tid == 0) counts[e] = runtot;
}

// ---------------- grouped GEMM: 128m x 256n tile, 8 waves of 64x64, BK=64, pinned ------
// r10 counters: FETCH 19.8MB (traffic solved by pinning) yet 43.9us with MfmaUtil 15% —
// LDS-port-bound: 64x32 wave tiles read 6 ds_read_b128 per 8 MFMA. 64x64 wave tiles
// halve that (8 reads per 16 MFMA): per-CU LDS pressure ~2300 -> ~770 cyc/iter.
// Single-buffered BK=64 (2x [.][32] sub-buffers, 64B rows), no dbuf (3x proven loss).
// Grid: 8m x 4n x 8e = 256 live blocks = 1 block/CU, 8 waves/CU, LDS 48 KB.
// LAYER==1: out = gelu(C + b1) -> bf16 abuf[(t,k) slot]
// LAYER==2: out = (C + b2) * gate -> f32 obuf[(t,k) slot]
template <int LAYER>
__global__ __launch_bounds__(512) void moe_gemm(
    const __hip_bfloat16* __restrict__ Abase,
    const __hip_bfloat16* __restrict__ Bbase,   // [E][N=1024][K=1024], K contiguous
    const float* __restrict__ bias,             // [E][1024]
    const int* __restrict__ rowmap,
    const int* __restrict__ counts,
    const float* __restrict__ gates,
    void* __restrict__ OutP)
{
    // decode: e = XCD selector (fastest) -> expert e's blocks land on XCD e
    const int bid = blockIdx.x;
    const int e = bid & 7;
    const int n0 = ((bid >> 3) & 3) * 256;
    const int m0 = (bid >> 5) * 128;
    const int cnt = counts[e];
    if (m0 >= cnt) return;
    const int tid = threadIdx.x;
    const int lane = tid & 63;
    const int wave = tid >> 6;
    const int wm = (wave >> 2) * 64;   // wave's 64m x 64n quadrant
    const int wn = (wave & 3) * 64;
    const int lrow = lane & 15;
    const int quad = lane >> 4;

    __shared__ __hip_bfloat16 As[2][128 * 32];   // 16 KB (64B rows: conflict-free)
    __shared__ __hip_bfloat16 Bs[2][256 * 32];   // 32 KB

    // staging map (lane-consecutive 16B): row = tid>>2, chunk = (tid&3)*8 elems;
    // wave w covers rows 16w..16w+15 -> dest = buf + w*1024 + lane*16. B needs 2 issues
    // (rows 0..127 and 128..255).
    const int ar = m0 + (tid >> 2);
    const int ea = rowmap[e * CAP + (ar < cnt ? ar : 0)];
    const size_t srcA = (size_t)(LAYER == 1 ? (ea >> 1) : ea);
    const __hip_bfloat16* gA = Abase + srcA * DD + (tid & 3) * 8;
    const __hip_bfloat16* Bexp = Bbase + (size_t)e * DD * HH;
    const __hip_bfloat16* gB0 = Bexp + (size_t)(n0 + (tid >> 2)) * DD + (tid & 3) * 8;
    const __hip_bfloat16* gB1 = gB0 + (size_t)128 * DD;

    f32x4 acc[4][4];
#pragma unroll
    for (int i = 0; i < 4; ++i)
#pragma unroll
        for (int j = 0; j < 4; ++j) acc[i][j] = (f32x4){0.f, 0.f, 0.f, 0.f};

    for (int kt = 0; kt < DD / 64; ++kt) {
#pragma unroll
        for (int s = 0; s < 2; ++s) {
            const int ko = kt * 64 + s * 32;
            GLL16(gA + ko, (char*)&As[s][0] + wave * 1024);
            GLL16(gB0 + ko, (char*)&Bs[s][0] + wave * 1024);
            GLL16(gB1 + ko, (char*)&Bs[s][0] + 8192 + wave * 1024);
        }
        __syncthreads();

#pragma unroll
        for (int s = 0; s < 2; ++s) {
            const bf16x8* Av = (const bf16x8*)&As[s][0];
            const bf16x8* Bv = (const bf16x8*)&Bs[s][0];
            bf16x8 af[4], bfr[4];
#pragma unroll
            for (int i = 0; i < 4; ++i)
                af[i] = Av[(wm + i * 16 + lrow) * 4 + quad];
#pragma unroll
            for (int i = 0; i < 4; ++i)
                bfr[i] = Bv[(wn + i * 16 + lrow) * 4 + quad];
#pragma unroll
            for (int mi = 0; mi < 4; ++mi)
#pragma unroll
                for (int ni = 0; ni < 4; ++ni)
                    acc[mi][ni] = __builtin_amdgcn_mfma_f32_16x16x32_bf16(
                        af[mi], bfr[ni], acc[mi][ni], 0, 0, 0);
        }
        __syncthreads();
    }

    // epilogue: C/D layout col = lane&15, row = quad*4 + reg (m89/m91 verified)
    if (LAYER == 1) {
        __hip_bfloat16* abuf = (__hip_bfloat16*)OutP;
#pragma unroll
        for (int mi = 0; mi < 4; ++mi) {
#pragma unroll
            for (int r = 0; r < 4; ++r) {
                const int mrow = wm + mi * 16 + quad * 4 + r;
                const int gm = m0 + mrow;
                if (gm < cnt) {
                    const int ent = rowmap[e * CAP + gm];
                    __hip_bfloat16* orow = abuf + (size_t)ent * HH + n0 + wn + lrow;
#pragma unroll
                    for (int ni = 0; ni < 4; ++ni) {
                        float v = acc[mi][ni][r] + bias[e * HH + n0 + wn + ni * 16 + lrow];
                        v = 0.5f * v * (1.f + erff(v * 0.70710678118654752f));  // exact GELU
                        orow[ni * 16] = __float2bfloat16(v);
                    }
                }
            }
        }
    } else {
        float* obuf = (float*)OutP;
#pragma unroll
        for (int mi = 0; mi < 4; ++mi) {
#pragma unroll
            for (int r = 0; r < 4; ++r) {
                const int mrow = wm + mi * 16 + quad * 4 + r;
                const int gm = m0 + mrow;
                if (gm < cnt) {
                    const int ent = rowmap[e * CAP + gm];
                    const float g = gates[ent];
                    float* orow = obuf + (size_t)ent * DD + n0 + wn + lrow;
#pragma unroll
                    for (int ni = 0; ni < 4; ++ni) {
                        float v = acc[mi][ni][r] + bias[e * DD + n0 + wn + ni * 16 + lrow];
                        orow[ni * 16] = v * g;
                    }
                }
            }
        }
    }
}

// ---------------- combine: y[t] = o[t,0] + o[t,1] ----------------
__global__ __launch_bounds__(256) void combine_kernel(
    const float* __restrict__ obuf, float* __restrict__ y)
{
    const size_t i = (size_t)blockIdx.x * 256 + threadIdx.x;
    const size_t t = i >> 8;
    const size_t c = i & 255;
    const float4* o0 = (const float4*)(obuf + t * 2 * DD);
    float4 a = o0[c];
    float4 b = o0[256 + c];
    float4 r;
    r.x = a.x + b.x; r.y = a.y + b.y; r.z = a.z + b.z; r.w = a.w + b.w;
    ((float4*)y)[i] = r;
}

extern "C" void kernel_launch(void* const* d_in, const int* in_sizes, int n_in,
                              void* d_out, int out_size, void* d_ws, size_t ws_size,
                              hipStream_t stream)
{
    const float* x  = (const float*)d_in[0];
    const float* w1 = (const float*)d_in[1];
    const float* b1 = (const float*)d_in[2];
    const float* w2 = (const float*)d_in[3];
    const float* b2 = (const float*)d_in[4];
    const float* wg = (const float*)d_in[5];
    float* y = (float*)d_out;

    char* ws = (char*)d_ws;
    __hip_bfloat16* xb   = (__hip_bfloat16*)(ws + OFF_XB);
    __hip_bfloat16* w1t  = (__hip_bfloat16*)(ws + OFF_W1T);
    __hip_bfloat16* w2t  = (__hip_bfloat16*)(ws + OFF_W2T);
    __hip_bfloat16* abuf = (__hip_bfloat16*)(ws + OFF_ABUF);
    float* obuf  = (float*)(ws + OFF_OBUF);
    int*   rowmap = (int*)(ws + OFF_ROWMAP);
    float* gates  = (float*)(ws + OFF_GATES);
    int*   counts = (int*)(ws + OFF_COUNTS);
    int*   picks  = (int*)(ws + OFF_PICKS);

    prep_kernel<<<NGATE + 4096, 256, 0, stream>>>(x, wg, w1, w2, xb, w1t, w2t, picks, gates);
    bucket_build<<<EE, 256, 0, stream>>>(picks, rowmap, counts);
    // 1D grid: id = (m<<5) | (n<<3) | e  -> expert = XCD selector; 4 n-tiles of 256
    moe_gemm<1><<<(CAP / 128) * 4 * EE, 512, 0, stream>>>(
        xb, w1t, b1, rowmap, counts, gates, (void*)abuf);
    moe_gemm<2><<<(CAP / 128) * 4 * EE, 512, 0, stream>>>(
        abuf, w2t, b2, rowmap, counts, gates, (void*)obuf);
    combine_kernel<<<TT * DD / 4 / 256, 256, 0, stream>>>(obuf, y);
}

// Round 12
// 208.344 us; speedup vs baseline: 1.1134x; 1.0819x over previous
//
#include <hip/hip_runtime.h>
#include <hip/hip_bf16.h>
#include <math.h>

#define TT 4096
#define EE 8
#define DD 1024
#define HH 1024
#define CAP 4096

typedef __attribute__((ext_vector_type(8))) short bf16x8;
typedef __attribute__((ext_vector_type(4))) float f32x4;
typedef __attribute__((ext_vector_type(8))) unsigned short ushort8;

// async global->LDS, 16B per lane; LDS dest is wave-uniform base + lane*16
#define GLL16(gp, lp)                                                                   \
    __builtin_amdgcn_global_load_lds((__attribute__((address_space(1))) void*)(gp),     \
                                     (__attribute__((address_space(3))) void*)(lp),     \
                                     16, 0, 0)

// ---------------- workspace layout (bytes) ----------------
static const size_t OFF_XB     = 0;                         // bf16 [4096][1024]  8 MB
static const size_t OFF_W1T    = 8u * 1024 * 1024;          // bf16 [8][H][D]    16 MB
static const size_t OFF_W2T    = 24u * 1024 * 1024;         // bf16 [8][D][H]    16 MB
static const size_t OFF_ABUF   = 40u * 1024 * 1024;         // bf16 [8192][1024] 16 MB
static const size_t OFF_OBUF   = 56u * 1024 * 1024;         // f32  [8192][1024] 32 MB
static const size_t OFF_ROWMAP = 88u * 1024 * 1024;         // int  [8][4096]   128 KB
static const size_t OFF_GATES  = OFF_ROWMAP + 8 * CAP * 4;  // f32  [8192]       32 KB
static const size_t OFF_COUNTS = OFF_GATES + 8192 * 4;      // int  [8]
static const size_t OFF_PICKS  = OFF_COUNTS + 256;          // int  [4096]       16 KB

#define NGATE 1024

// 64x64 fp32->bf16 transpose of one tile using a 256-thread group + its own LDS tile.
// tl must point to float[64][65] (16640 B). Caller supplies group-local tid (0..255).
__device__ __forceinline__ void transpose_tile(
    const float* __restrict__ src, __hip_bfloat16* __restrict__ dst,
    int R, int C, float (*tl)[65], int t256)
{
    const int lrow = t256 >> 4;
    const int c4 = t256 & 15;
#pragma unroll
    for (int i = 0; i < 4; ++i) {
        const int r = lrow + i * 16;
        float4 v = *(const float4*)(src + (size_t)(R + r) * 1024 + C + c4 * 4);
        tl[r][c4 * 4 + 0] = v.x;
        tl[r][c4 * 4 + 1] = v.y;
        tl[r][c4 * 4 + 2] = v.z;
        tl[r][c4 * 4 + 3] = v.w;
    }
    __syncthreads();
    const int seg = t256 & 7;
    const int orow0 = t256 >> 3;
#pragma unroll
    for (int p = 0; p < 2; ++p) {
        const int orow = orow0 + p * 32;
        ushort8 u;
#pragma unroll
        for (int j = 0; j < 8; ++j) {
            __hip_bfloat16 h = __float2bfloat16(tl[seg * 8 + j][orow]);
            u[j] = *(unsigned short*)&h;
        }
        *(ushort8*)(dst + (size_t)(C + orow) * 1024 + R + seg * 8) = u;
    }
}

// ---------------- prep: gating (blocks 0..1023) + w1 transpose (1024..3071) ----------
__global__ __launch_bounds__(256) void prep_kernel(
    const float* __restrict__ x, const float* __restrict__ wg,
    const float* __restrict__ w1,
    __hip_bfloat16* __restrict__ xb, __hip_bfloat16* __restrict__ w1t,
    int* __restrict__ picks, float* __restrict__ gates)
{
    __shared__ float tl[64][65];
    const int bid = blockIdx.x;
    const int tid = threadIdx.x;

    if (bid >= NGATE) {
        const int bt = bid - NGATE;          // 0..2047: 8 matrices x 256 tiles
        const int mat = bt >> 8;
        const int tt = bt & 255;
        transpose_tile(w1 + (size_t)mat * DD * HH, w1t + (size_t)mat * DD * HH,
                       (tt >> 4) * 64, (tt & 15) * 64, tl, tid);
        return;
    }

    // ---- gate path: one token per wave ----
    const int lane = tid & 63;
    const int wave = tid >> 6;
    const int t = bid * 4 + wave;
    {
        const float4* xr = (const float4*)(x + (size_t)t * DD);
        ushort4* xbr = (ushort4*)(xb + (size_t)t * DD);

        float acc[EE];
#pragma unroll
        for (int e = 0; e < EE; ++e) acc[e] = 0.f;

#pragma unroll
        for (int c = 0; c < 4; ++c) {
            const int v4 = lane + 64 * c;
            float4 xv = xr[v4];
            __hip_bfloat16 h0 = __float2bfloat16(xv.x);
            __hip_bfloat16 h1 = __float2bfloat16(xv.y);
            __hip_bfloat16 h2 = __float2bfloat16(xv.z);
            __hip_bfloat16 h3 = __float2bfloat16(xv.w);
            ushort4 s;
            s.x = *(unsigned short*)&h0; s.y = *(unsigned short*)&h1;
            s.z = *(unsigned short*)&h2; s.w = *(unsigned short*)&h3;
            xbr[v4] = s;
            const float4* wrow = (const float4*)(wg + (size_t)(4 * v4) * EE);
            const float xs[4] = {xv.x, xv.y, xv.z, xv.w};
#pragma unroll
            for (int q = 0; q < 4; ++q) {
                float4 w0 = wrow[q * 2];
                float4 w1v = wrow[q * 2 + 1];
                acc[0] = fmaf(xs[q], w0.x, acc[0]);
                acc[1] = fmaf(xs[q], w0.y, acc[1]);
                acc[2] = fmaf(xs[q], w0.z, acc[2]);
                acc[3] = fmaf(xs[q], w0.w, acc[3]);
                acc[4] = fmaf(xs[q], w1v.x, acc[4]);
                acc[5] = fmaf(xs[q], w1v.y, acc[5]);
                acc[6] = fmaf(xs[q], w1v.z, acc[6]);
                acc[7] = fmaf(xs[q], w1v.w, acc[7]);
            }
        }
#pragma unroll
        for (int off = 32; off > 0; off >>= 1) {
#pragma unroll
            for (int e = 0; e < EE; ++e) acc[e] += __shfl_xor(acc[e], off, 64);
        }
        if (lane == 0) {
            float mx = acc[0];
#pragma unroll
            for (int e = 1; e < EE; ++e) mx = fmaxf(mx, acc[e]);
            float p[EE];
            float s = 0.f;
#pragma unroll
            for (int e = 0; e < EE; ++e) { p[e] = expf(acc[e] - mx); s += p[e]; }
            int i0 = 0;
#pragma unroll
            for (int e = 1; e < EE; ++e) if (acc[e] > acc[i0]) i0 = e;
            int i1 = (i0 == 0) ? 1 : 0;
#pragma unroll
            for (int e = 0; e < EE; ++e) {
                if (e != i0 && acc[e] > acc[i1]) i1 = e;
            }
            float v0 = p[i0] / s, v1 = p[i1] / s;
            float den = v0 + v1 + 1e-6f;
            gates[t * 2 + 0] = v0 / den;
            gates[t * 2 + 1] = v1 / den;
            picks[t] = i0 | (i1 << 4);
        }
    }
}

// ---------------- bucket build (deterministic, no global atomics) ----------------
__global__ __launch_bounds__(256) void bucket_build(
    const int* __restrict__ picks, int* __restrict__ rowmap, int* __restrict__ counts)
{
    const int e = blockIdx.x;
    const int tid = threadIdx.x;
    const int lane = tid & 63;
    const int wave = tid >> 6;
    __shared__ int wsum[4];

    int runtot = 0;
    for (int tb = 0; tb < TT; tb += 256) {
        const int t = tb + tid;
        const int p = picks[t];
        const int m0 = ((p & 15) == e) ? 1 : 0;
        const int m1 = (((p >> 4) & 15) == e) ? 1 : 0;
        const int c = m0 + m1;
        int incl = c;
#pragma unroll
        for (int off = 1; off < 64; off <<= 1) {
            int v = __shfl_up(incl, off, 64);
            if (lane >= off) incl += v;
        }
        if (lane == 63) wsum[wave] = incl;
        __syncthreads();
        int wbase = 0;
#pragma unroll
        for (int w = 0; w < 4; ++w) wbase += (w < wave) ? wsum[w] : 0;
        int slot = runtot + wbase + incl - c;
        if (m0) { rowmap[e * CAP + slot] = t * 2; slot += 1; }
        if (m1) { rowmap[e * CAP + slot] = t * 2 + 1; }
        runtot += wsum[0] + wsum[1] + wsum[2] + wsum[3];
        __syncthreads();
    }
    if (tid == 0) counts[e] = runtot;
}

// ---------------- grouped GEMM: exact r9 best config (128x128, 512thr, BK=64, pinned) --
// r9 = session-best GEMM (<40us, total 214). Six variants since all landed 43-50us.
// LAYER==1 additionally carries 1024 w2-transpose blocks (ids >= 2048): they have no
// dependency on gemm1's output, dispatch after the gemm blocks seed the CUs, and hide
// under gemm1's idle slack (MfmaUtil 15%, HBM 10%). LDS is a union (gemm 32KB /
// transpose 2x16.6KB).
// LAYER==1: out = gelu(C + b1) -> bf16 abuf[(t,k) slot]
// LAYER==2: out = (C + b2) * gate -> f32 obuf[(t,k) slot]
template <int LAYER>
__global__ __launch_bounds__(512) void moe_gemm(
    const __hip_bfloat16* __restrict__ Abase,
    const __hip_bfloat16* __restrict__ Bbase,   // [E][N=1024][K=1024], K contiguous
    const float* __restrict__ bias,             // [E][1024]
    const int* __restrict__ rowmap,
    const int* __restrict__ counts,
    const float* __restrict__ gates,
    void* __restrict__ OutP,
    const float* __restrict__ wsrc,             // LAYER==1: w2 (fp32)
    __hip_bfloat16* __restrict__ wdst)          // LAYER==1: w2t
{
    alignas(16) __shared__ char raw[33280];     // union: gemm 32KB | transpose 2x16640B
    const int bid = blockIdx.x;
    const int tid = threadIdx.x;

    if (LAYER == 1 && bid >= 2048) {
        // ---- fused w2 transpose: 2 tiles per 512-thread block ----
        const int half = tid >> 8;
        const int tile = (bid - 2048) * 2 + half;   // 0..2047
        const int mat = tile >> 8;
        const int tt = tile & 255;
        float (*tl)[65] = (float(*)[65])(raw + half * 16640);
        transpose_tile(wsrc + (size_t)mat * DD * HH, wdst + (size_t)mat * DD * HH,
                       (tt >> 4) * 64, (tt & 15) * 64, tl, tid & 255);
        return;
    }

    // decode: e = XCD selector (fastest) -> expert e's blocks land on XCD e
    const int e = bid & 7;
    const int n0 = ((bid >> 3) & 7) * 128;
    const int m0 = (bid >> 6) * 128;
    const int cnt = counts[e];
    if (m0 >= cnt) return;
    const int lane = tid & 63;
    const int wave = tid >> 6;
    const int wm = (wave >> 2) * 64;   // wave's 64m x 32n quadrant
    const int wn = (wave & 3) * 32;
    const int lrow = lane & 15;
    const int quad = lane >> 4;

    __hip_bfloat16* As = (__hip_bfloat16*)raw;             // [2][128*32], 16 KB
    __hip_bfloat16* Bs = (__hip_bfloat16*)(raw + 16384);   // [2][128*32], 16 KB

    // staging: row = tid>>2 (0..127), 16B chunk = (tid&3)*8 elems; wave w covers rows
    // 16w..16w+15 -> LDS dest = buf + w*1024 + lane*16 (wave-uniform base + lane*16)
    const int ar = m0 + (tid >> 2);
    const int ea = rowmap[e * CAP + (ar < cnt ? ar : 0)];
    const size_t srcA = (size_t)(LAYER == 1 ? (ea >> 1) : ea);
    const __hip_bfloat16* gA = Abase + srcA * DD + (tid & 3) * 8;
    const __hip_bfloat16* Bexp = Bbase + (size_t)e * DD * HH;
    const __hip_bfloat16* gB = Bexp + (size_t)(n0 + (tid >> 2)) * DD + (tid & 3) * 8;

    f32x4 acc[4][2];
#pragma unroll
    for (int i = 0; i < 4; ++i)
#pragma unroll
        for (int j = 0; j < 2; ++j) acc[i][j] = (f32x4){0.f, 0.f, 0.f, 0.f};

    for (int kt = 0; kt < DD / 64; ++kt) {
#pragma unroll
        for (int s = 0; s < 2; ++s) {
            const int ko = kt * 64 + s * 32;
            GLL16(gA + ko, As + s * 4096 + wave * 512);   // +wave*1024B via bf16*512
            GLL16(gB + ko, Bs + s * 4096 + wave * 512);
        }
        __syncthreads();

#pragma unroll
        for (int s = 0; s < 2; ++s) {
            const bf16x8* Av = (const bf16x8*)(As + s * 4096);
            const bf16x8* Bv = (const bf16x8*)(Bs + s * 4096);
            bf16x8 af[4], bfr[2];
#pragma unroll
            for (int i = 0; i < 4; ++i)
                af[i] = Av[(wm + i * 16 + lrow) * 4 + quad];
#pragma unroll
            for (int i = 0; i < 2; ++i)
                bfr[i] = Bv[(wn + i * 16 + lrow) * 4 + quad];
#pragma unroll
            for (int mi = 0; mi < 4; ++mi)
#pragma unroll
                for (int ni = 0; ni < 2; ++ni)
                    acc[mi][ni] = __builtin_amdgcn_mfma_f32_16x16x32_bf16(
                        af[mi], bfr[ni], acc[mi][ni], 0, 0, 0);
        }
        __syncthreads();
    }

    // epilogue: C/D layout col = lane&15, row = quad*4 + reg (m89/m91 verified)
    if (LAYER == 1) {
        __hip_bfloat16* abuf = (__hip_bfloat16*)OutP;
#pragma unroll
        for (int mi = 0; mi < 4; ++mi) {
#pragma unroll
            for (int r = 0; r < 4; ++r) {
                const int mrow = wm + mi * 16 + quad * 4 + r;
                const int gm = m0 + mrow;
                if (gm < cnt) {
                    const int ent = rowmap[e * CAP + gm];
                    __hip_bfloat16* orow = abuf + (size_t)ent * HH + n0 + wn + lrow;
#pragma unroll
                    for (int ni = 0; ni < 2; ++ni) {
                        float v = acc[mi][ni][r] + bias[e * HH + n0 + wn + ni * 16 + lrow];
                        v = 0.5f * v * (1.f + erff(v * 0.70710678118654752f));  // exact GELU
                        orow[ni * 16] = __float2bfloat16(v);
                    }
                }
            }
        }
    } else {
        float* obuf = (float*)OutP;
#pragma unroll
        for (int mi = 0; mi < 4; ++mi) {
#pragma unroll
            for (int r = 0; r < 4; ++r) {
                const int mrow = wm + mi * 16 + quad * 4 + r;
                const int gm = m0 + mrow;
                if (gm < cnt) {
                    const int ent = rowmap[e * CAP + gm];
                    const float g = gates[ent];
                    float* orow = obuf + (size_t)ent * DD + n0 + wn + lrow;
#pragma unroll
                    for (int ni = 0; ni < 2; ++ni) {
                        float v = acc[mi][ni][r] + bias[e * DD + n0 + wn + ni * 16 + lrow];
                        orow[ni * 16] = v * g;
                    }
                }
            }
        }
    }
}

// ---------------- combine: y[t] = o[t,0] + o[t,1], 2 float4 per thread ----------------
__global__ __launch_bounds__(256) void combine_kernel(
    const float* __restrict__ obuf, float* __restrict__ y)
{
#pragma unroll
    for (int k = 0; k < 2; ++k) {
        const size_t i = (size_t)blockIdx.x * 512 + k * 256 + threadIdx.x;
        const size_t t = i >> 8;
        const size_t c = i & 255;
        const float4* o0 = (const float4*)(obuf + t * 2 * DD);
        float4 a = o0[c];
        float4 b = o0[256 + c];
        float4 r;
        r.x = a.x + b.x; r.y = a.y + b.y; r.z = a.z + b.z; r.w = a.w + b.w;
        ((float4*)y)[i] = r;
    }
}

extern "C" void kernel_launch(void* const* d_in, const int* in_sizes, int n_in,
                              void* d_out, int out_size, void* d_ws, size_t ws_size,
                              hipStream_t stream)
{
    const float* x  = (const float*)d_in[0];
    const float* w1 = (const float*)d_in[1];
    const float* b1 = (const float*)d_in[2];
    const float* w2 = (const float*)d_in[3];
    const float* b2 = (const float*)d_in[4];
    const float* wg = (const float*)d_in[5];
    float* y = (float*)d_out;

    char* ws = (char*)d_ws;
    __hip_bfloat16* xb   = (__hip_bfloat16*)(ws + OFF_XB);
    __hip_bfloat16* w1t  = (__hip_bfloat16*)(ws + OFF_W1T);
    __hip_bfloat16* w2t  = (__hip_bfloat16*)(ws + OFF_W2T);
    __hip_bfloat16* abuf = (__hip_bfloat16*)(ws + OFF_ABUF);
    float* obuf  = (float*)(ws + OFF_OBUF);
    int*   rowmap = (int*)(ws + OFF_ROWMAP);
    float* gates  = (float*)(ws + OFF_GATES);
    int*   counts = (int*)(ws + OFF_COUNTS);
    int*   picks  = (int*)(ws + OFF_PICKS);

    // gate (1024) + w1-transpose (2048)
    prep_kernel<<<NGATE + 2048, 256, 0, stream>>>(x, wg, w1, xb, w1t, picks, gates);
    bucket_build<<<EE, 256, 0, stream>>>(picks, rowmap, counts);
    // gemm1 (2048 ids, e = bid&7 XCD pin) + fused w2-transpose (1024 ids after)
    moe_gemm<1><<<2048 + 1024, 512, 0, stream>>>(
        xb, w1t, b1, rowmap, counts, gates, (void*)abuf, w2, w2t);
    moe_gemm<2><<<2048, 512, 0, stream>>>(
        abuf, w2t, b2, rowmap, counts, gates, (void*)obuf, nullptr, nullptr);
    combine_kernel<<<TT * DD / 4 / 512, 256, 0, stream>>>(obuf, y);
}